// Round 5
// baseline (606.628 us; speedup 1.0000x reference)
//
#include <hip/hip_runtime.h>
#include <hip/hip_bf16.h>
#include <cstdint>

// ---------------- problem dims ----------------
#define BS 8
#define SEQ 2048
#define HDIM 1024
#define NH 16
#define HD 64
#define M_ROWS (BS * SEQ)   // 16384
#define N_COLS (2 * HDIM)   // 2048 GEMM cols: 0..1023 = K1 (dots only), 1024..2047 = V1
#define KDIM HDIM           // 1024

#define DELTA 0.025f
#define PER_HEAD_CAP 8192        // flagged (b,l) per head; expected ~390, cap >> tail
#define TASKS_PER_WAVE 8
#define GROUPS_PER_HEAD (PER_HEAD_CAP / TASKS_PER_WAVE)   // 1024

// ---------------- workspace layout (bytes) ----------------
#define OFF_A      ((size_t)0)           // bf16 A [M,K]             33,554,432
#define OFF_BT     ((size_t)33554432)    // bf16 Bt [N,K]             4,194,304
#define OFF_FCNT   ((size_t)37748736)    // int[16]
#define OFF_FLIST  ((size_t)37748800)    // int[16][8192]               524,288
#define OFF_BIAS   ((size_t)38273088)    // f32 [2048]
#define OFF_CV     ((size_t)41943040)    // f32 CV [M,1024] (V1 only) 67,108,864
#define OFF_VALID  ((size_t)109051904)   // u8 [BS][NH][SEQ]             262,144
#define OFF_MAPS   ((size_t)109314048)   // ushort4 [BS][SEQ][NH]      2,097,152
// total ~111.4 MB

typedef __attribute__((ext_vector_type(8))) __bf16 bf16x8;
typedef __attribute__((ext_vector_type(4))) float f32x4;

// float -> bf16 bits, round-to-nearest-even (inputs are finite)
__device__ __forceinline__ unsigned short f2bf(float f) {
    unsigned int x = __builtin_bit_cast(unsigned int, f);
    unsigned int r = x + 0x7fffu + ((x >> 16) & 1u);
    return (unsigned short)(r >> 16);
}

// async 16B global -> LDS (dest = wave-uniform LDS base + lane*16)
__device__ __forceinline__ void g2l16(const void* gp, void* lp) {
    __builtin_amdgcn_global_load_lds(
        (__attribute__((address_space(1))) void*)(void*)gp,
        (__attribute__((address_space(3))) void*)lp, 16, 0, 0);
}

// ---------------- prep kernels ----------------
__global__ __launch_bounds__(256) void cvt_hs_kernel(const float4* __restrict__ in,
                                                     ushort4* __restrict__ outp) {
    int i = blockIdx.x * 256 + threadIdx.x;   // 4,194,304 total
    float4 v = in[i];
    ushort4 o;
    o.x = f2bf(v.x); o.y = f2bf(v.y); o.z = f2bf(v.z); o.w = f2bf(v.w);
    outp[i] = o;
}

// transpose W [K=1024][N=1024] -> Bt[n][k] (bf16)
__global__ __launch_bounds__(256) void cvt_w_kernel(const float* __restrict__ K1w,
                                                    const float* __restrict__ V1w,
                                                    unsigned short* __restrict__ Bt) {
    __shared__ float tile[32][33];
    const float* W = blockIdx.z ? V1w : K1w;
    int tn = blockIdx.x, tk = blockIdx.y;
    int t = threadIdx.x;
    int r = t >> 3;            // 0..31
    int c4 = (t & 7) * 4;      // 0,4,..,28
    const float4 v = *(const float4*)&W[(size_t)(tk * 32 + r) * 1024 + tn * 32 + c4];
    tile[r][c4 + 0] = v.x; tile[r][c4 + 1] = v.y; tile[r][c4 + 2] = v.z; tile[r][c4 + 3] = v.w;
    __syncthreads();
    int n = tn * 32 + r;
    int k = tk * 32 + c4;
    float f0 = tile[c4 + 0][r], f1 = tile[c4 + 1][r], f2 = tile[c4 + 2][r], f3 = tile[c4 + 3][r];
    size_t obase = ((size_t)blockIdx.z * 1024 + n) * 1024 + k;
    ushort4 o; o.x = f2bf(f0); o.y = f2bf(f1); o.z = f2bf(f2); o.w = f2bf(f3);
    *(ushort4*)&Bt[obase] = o;
}

__global__ void cvt_bias_kernel(const float* __restrict__ K1b, const float* __restrict__ V1b,
                                float* __restrict__ bias, int* __restrict__ fcnt) {
    int i = blockIdx.x * 256 + threadIdx.x;   // 2048 total
    bias[i] = (i < 1024) ? K1b[i] : V1b[i - 1024];
    if (i < 16) fcnt[i] = 0;
}

// ---------------- GEMM + fused dots ----------------
// A [M,K] bf16, Bt [N,K] bf16. 128x128 tile, BK=32, 4 waves 2x2.
// Blocks with n0 <  1024: each wave's 64x64 block == one head's K1 slab ->
//   compute dots = sum_d relu(acc+bias)*RH in-register, write valid + flag list.
//   K-half of C is NEVER stored.
// Blocks with n0 >= 1024: store relu(acc+bias) into CV [M][1024].
__global__ __launch_bounds__(256) void gemm_kernel(const unsigned short* __restrict__ Abf,
                                                   const unsigned short* __restrict__ Btbf,
                                                   const float* __restrict__ bias,
                                                   const float* __restrict__ RH,
                                                   float* __restrict__ CV,
                                                   unsigned char* __restrict__ valid,
                                                   int* __restrict__ fcnt,
                                                   int* __restrict__ flist) {
    constexpr int K = KDIM, BK = 32;
    __shared__ unsigned short As[128 * BK];   // row-major [128][32]
    __shared__ unsigned short Bs[128 * BK];
    const int t = threadIdx.x;
    const int wave = t >> 6, lane = t & 63;
    const int wm = wave >> 1, wn = wave & 1;
    const int l16 = lane & 15, quad = lane >> 4;
    const int m0 = blockIdx.y * 128, n0 = blockIdx.x * 128;

    f32x4 zero4 = {0.f, 0.f, 0.f, 0.f};
    f32x4 acc[4][4];
#pragma unroll
    for (int i = 0; i < 4; i++)
#pragma unroll
        for (int j = 0; j < 4; j++) acc[i][j] = zero4;

    const int srow = t >> 2;          // 0..63
    const int sk = (t & 3) * 8;       // k element offset of this lane's 16B
    const unsigned short* gA = Abf + (size_t)(m0 + srow) * K + sk;
    const unsigned short* gB = Btbf + (size_t)(n0 + srow) * K + sk;
    char* lAs = (char*)As + (size_t)wave * 1024;
    char* lBs = (char*)Bs + (size_t)wave * 1024;

    for (int k0 = 0; k0 < K; k0 += BK) {
        g2l16(gA + k0, lAs);
        g2l16(gA + (size_t)64 * K + k0, lAs + 4096);
        g2l16(gB + k0, lBs);
        g2l16(gB + (size_t)64 * K + k0, lBs + 4096);
        __syncthreads();   // drains global_load_lds (vmcnt) + barrier
        bf16x8 af[4], bfr[4];
#pragma unroll
        for (int mt = 0; mt < 4; mt++)
            af[mt] = *(const bf16x8*)&As[(wm * 64 + mt * 16 + l16) * BK + quad * 8];
#pragma unroll
        for (int nt = 0; nt < 4; nt++)
            bfr[nt] = *(const bf16x8*)&Bs[(wn * 64 + nt * 16 + l16) * BK + quad * 8];
#pragma unroll
        for (int mt = 0; mt < 4; mt++)
#pragma unroll
            for (int nt = 0; nt < 4; nt++)
                acc[mt][nt] = __builtin_amdgcn_mfma_f32_16x16x32_bf16(af[mt], bfr[nt], acc[mt][nt], 0, 0, 0);
        __syncthreads();
    }
    // C/D fragment: row = quad*4 + reg, col = l16 (within each 16x16 tile)
    if (n0 < HDIM) {
        // ---- fused dots: this wave's head ----
        const int n = (n0 >> 6) + wn;
        float rh[4], bv[4];
#pragma unroll
        for (int nt = 0; nt < 4; nt++) {
            int col = n * 64 + nt * 16 + l16;
            rh[nt] = RH[col];
            bv[nt] = bias[col];
        }
#pragma unroll
        for (int mt = 0; mt < 4; mt++) {
#pragma unroll
            for (int r = 0; r < 4; r++) {
                float p = 0.f;
#pragma unroll
                for (int nt = 0; nt < 4; nt++)
                    p += fmaxf(acc[mt][nt][r] + bv[nt], 0.f) * rh[nt];
#pragma unroll
                for (int s = 8; s >= 1; s >>= 1) p += __shfl_xor(p, s, 64);
                if (l16 == 0) {
                    int row = m0 + wm * 64 + mt * 16 + quad * 4 + r;   // b*SEQ + l
                    int b = row >> 11, l = row & (SEQ - 1);
                    valid[((size_t)b * NH + n) * SEQ + l] = (p > 0.5f) ? 1 : 0;
                    if (fabsf(p - 0.5f) < DELTA) {
                        int idx = atomicAdd(&fcnt[n], 1);
                        if (idx < PER_HEAD_CAP) flist[n * PER_HEAD_CAP + idx] = row;
                    }
                }
            }
        }
    } else {
        // ---- V-half: bias + relu, store to CV ----
        const int nv0 = n0 - HDIM;
#pragma unroll
        for (int mt = 0; mt < 4; mt++) {
            int gm = m0 + wm * 64 + mt * 16 + quad * 4;
#pragma unroll
            for (int nt = 0; nt < 4; nt++) {
                int gn = nv0 + wn * 64 + nt * 16 + l16;
                float bvv = bias[HDIM + gn];
#pragma unroll
                for (int r = 0; r < 4; r++)
                    CV[(size_t)(gm + r) * HDIM + gn] = fmaxf(acc[mt][nt][r] + bvv, 0.f);
            }
        }
    }
}

// ---------------- exact fp64 refinement, software-pipelined ----------------
// One 64-thread block = one wave = 8 tasks of head n. Lane d owns dim d.
// Per k-quad: 4 coalesced weight dwords (shared by all 8 tasks) + 8
// wave-uniform float4 x loads. Explicit 1-deep prefetch: k+4's 12 loads are
// issued into NAMED next-buffers before k's 32 v_fma_f64 consume the current
// buffers -> ~44 live floats force the register allocator to give us MLP
// (the R4 failure was VGPR=36 -> serialized loads at full L2 latency).
__global__ __launch_bounds__(64) void refine_kernel(const float* __restrict__ hs,
                                                    const float* __restrict__ K1w,
                                                    const float* __restrict__ K1b,
                                                    const float* __restrict__ RH,
                                                    const int* __restrict__ fcnt,
                                                    const int* __restrict__ flist,
                                                    unsigned char* __restrict__ valid) {
    const int n = blockIdx.x / GROUPS_PER_HEAD;
    const int g = blockIdx.x & (GROUPS_PER_HEAD - 1);
    int cnt = fcnt[n];
    if (cnt > PER_HEAD_CAP) cnt = PER_HEAD_CAP;
    const int tbase = g * TASKS_PER_WAVE;
    if (tbase >= cnt) return;
    const int d = threadIdx.x;   // 0..63

    int bl[8];
    const float* xp[8];
#pragma unroll
    for (int j = 0; j < 8; j++) {
        int idx = tbase + j;
        bl[j] = (idx < cnt) ? flist[n * PER_HEAD_CAP + idx] : -1;
        xp[j] = hs + (size_t)(bl[j] < 0 ? 0 : bl[j]) * HDIM;
    }
    const float* wp = K1w + n * 64 + d;     // stride 1024 over k, lane-coalesced

    double acc[8];
#pragma unroll
    for (int j = 0; j < 8; j++) acc[j] = 0.0;

    // prologue: prefetch k=0
    float wc0 = wp[0], wc1 = wp[1024], wc2 = wp[2048], wc3 = wp[3072];
    float4 xc[8];
#pragma unroll
    for (int j = 0; j < 8; j++) xc[j] = *(const float4*)(xp[j]);

    for (int k = 0; k < KDIM; k += 4) {
        const int k2 = (k + 4) & (KDIM - 1);   // last iter harmlessly reloads k=0
        const float* wpn = wp + (size_t)k2 * 1024;
        float wn0 = wpn[0], wn1 = wpn[1024], wn2 = wpn[2048], wn3 = wpn[3072];
        float4 xn[8];
#pragma unroll
        for (int j = 0; j < 8; j++) xn[j] = *(const float4*)(xp[j] + k2);
        const double dw0 = (double)wc0, dw1 = (double)wc1;
        const double dw2 = (double)wc2, dw3 = (double)wc3;
#pragma unroll
        for (int j = 0; j < 8; j++) {
            acc[j] += (double)xc[j].x * dw0;
            acc[j] += (double)xc[j].y * dw1;
            acc[j] += (double)xc[j].z * dw2;
            acc[j] += (double)xc[j].w * dw3;
        }
        wc0 = wn0; wc1 = wn1; wc2 = wn2; wc3 = wn3;
#pragma unroll
        for (int j = 0; j < 8; j++) xc[j] = xn[j];
    }

    const double bias_d = (double)K1b[n * 64 + d];
    const double rh_d = (double)RH[n * 64 + d];
#pragma unroll
    for (int j = 0; j < 8; j++) {
        double k1 = acc[j] + bias_d;
        if (k1 < 0.0) k1 = 0.0;
        double contrib = k1 * rh_d;
#pragma unroll
        for (int s = 32; s >= 1; s >>= 1) contrib += __shfl_xor(contrib, s, 64);
        if (d == 0 && bl[j] >= 0) {
            int b = bl[j] >> 11, l = bl[j] & (SEQ - 1);
            valid[((size_t)b * NH + n) * SEQ + l] = (contrib > 0.5) ? 1 : 0;
        }
    }
}

// ---------------- nearest-valid scans ----------------
// one block (64 threads) per (b,n). Lane i owns positions [32i, 32i+32).
__global__ __launch_bounds__(64) void scan_kernel(const unsigned char* __restrict__ valid,
                                                  ushort4* __restrict__ maps) {
    int bn = blockIdx.x;                 // b*NH + n
    int b = bn >> 4, n = bn & (NH - 1);
    int lane = threadIdx.x;
    __shared__ unsigned int summ[64];

    const unsigned char* vp = valid + (size_t)bn * SEQ + lane * 32;
    uint4 c0 = *(const uint4*)vp;
    uint4 c1 = *(const uint4*)(vp + 16);
    unsigned int wds[8] = {c0.x, c0.y, c0.z, c0.w, c1.x, c1.y, c1.z, c1.w};
    unsigned int mask = 0;
#pragma unroll
    for (int i = 0; i < 8; i++) {
#pragma unroll
        for (int j = 0; j < 4; j++)
            mask |= (((wds[i] >> (8 * j)) & 0xffu) ? 1u : 0u) << (i * 4 + j);
    }

    // ---- forward ----
    int cnt = 0, va = 0, vb = 0;
#pragma unroll
    for (int tt = 0; tt < 32; tt++) {
        if (mask & (1u << tt)) { vb = va; va = lane * 32 + tt; cnt++; }
    }
    summ[lane] = (unsigned)((cnt > 2 ? 2 : cnt) | (va << 2) | (vb << 13));
    __syncthreads();
    int a = 0, bb_ = 0;
    for (int tt = 0; tt < lane; tt++) {
        unsigned s = summ[tt];
        int c = s & 3, sva = (s >> 2) & 2047, svb = (s >> 13) & 2047;
        if (c >= 2) { a = sva; bb_ = svb; }
        else if (c == 1) { bb_ = a; a = sva; }
    }
    unsigned int fres[32];
#pragma unroll
    for (int tt = 0; tt < 32; tt++) {
        if (mask & (1u << tt)) { bb_ = a; a = lane * 32 + tt; }
        fres[tt] = (unsigned)a | ((unsigned)bb_ << 16);
    }
    __syncthreads();

    // ---- backward (mirrored values) ----
    unsigned int maskb = mask;
    if (lane == 63) maskb &= ~(1u << 31);   // exclude j = L-1
    cnt = 0; va = 0; vb = 0;
#pragma unroll
    for (int tt = 31; tt >= 0; tt--) {
        if (maskb & (1u << tt)) { vb = va; va = (SEQ - 1) - (lane * 32 + tt); cnt++; }
    }
    summ[lane] = (unsigned)((cnt > 2 ? 2 : cnt) | (va << 2) | (vb << 13));
    __syncthreads();
    int a2 = SEQ - 1, b2 = SEQ - 1;
    for (int tt = 63; tt > lane; tt--) {
        unsigned s = summ[tt];
        int c = s & 3, sva = (s >> 2) & 2047, svb = (s >> 13) & 2047;
        if (c >= 2) { a2 = sva; b2 = svb; }
        else if (c == 1) { b2 = a2; a2 = sva; }
    }
#pragma unroll
    for (int tt = 31; tt >= 0; tt--) {
        int j = lane * 32 + tt;
        if (maskb & (1u << tt)) { b2 = a2; a2 = (SEQ - 1) - j; }
        unsigned f = fres[tt];
        maps[((size_t)b * SEQ + j) * NH + n] =
            make_ushort4((unsigned short)(f & 0xffffu), (unsigned short)(f >> 16),
                         (unsigned short)a2, (unsigned short)b2);
    }
}

// ---------------- gather + weighted sum (CV layout [M][1024]) ----------------
__global__ __launch_bounds__(256) void gather_kernel(const float* __restrict__ CV,
                                                     const ushort4* __restrict__ maps,
                                                     const float* __restrict__ bw,
                                                     float* __restrict__ out) {
    int bl = blockIdx.x;
    int t = threadIdx.x, n = t >> 4, q = t & 15;
    int b = bl >> 11;
    ushort4 m = maps[(size_t)bl * NH + n];
    const float4 w = *(const float4*)&bw[n * 4];
    size_t colbase = (size_t)(n * 64 + q * 4);
    size_t rowb = (size_t)b * SEQ;
    const float4 v0 = *(const float4*)&CV[(rowb + m.x) * HDIM + colbase];
    const float4 v1 = *(const float4*)&CV[(rowb + m.y) * HDIM + colbase];
    const float4 v2 = *(const float4*)&CV[(rowb + m.z) * HDIM + colbase];
    const float4 v3 = *(const float4*)&CV[(rowb + m.w) * HDIM + colbase];
    float4 o;
    o.x = w.x * v0.x + w.y * v1.x + w.z * v2.x + w.w * v3.x;
    o.y = w.x * v0.y + w.y * v1.y + w.z * v2.y + w.w * v3.y;
    o.z = w.x * v0.z + w.y * v1.z + w.z * v2.z + w.w * v3.z;
    o.w = w.x * v0.w + w.y * v1.w + w.z * v2.w + w.w * v3.w;
    *(float4*)&out[(size_t)bl * (NH * HD) + n * 64 + q * 4] = o;
}

// ---------------- launch ----------------
extern "C" void kernel_launch(void* const* d_in, const int* in_sizes, int n_in,
                              void* d_out, int out_size, void* d_ws, size_t ws_size,
                              hipStream_t stream) {
    (void)in_sizes; (void)n_in; (void)out_size; (void)ws_size;
    const float* hs  = (const float*)d_in[0];
    const float* K1w = (const float*)d_in[1];
    const float* K1b = (const float*)d_in[2];
    const float* V1w = (const float*)d_in[3];
    const float* V1b = (const float*)d_in[4];
    const float* bw  = (const float*)d_in[5];
    const float* RH  = (const float*)d_in[6];
    float* out = (float*)d_out;
    char* ws = (char*)d_ws;

    unsigned short* Abf  = (unsigned short*)(ws + OFF_A);
    unsigned short* Btbf = (unsigned short*)(ws + OFF_BT);
    int* fcnt = (int*)(ws + OFF_FCNT);
    int* flist = (int*)(ws + OFF_FLIST);
    float* bias  = (float*)(ws + OFF_BIAS);
    float* CV    = (float*)(ws + OFF_CV);
    unsigned char* valid = (unsigned char*)(ws + OFF_VALID);
    ushort4* maps = (ushort4*)(ws + OFF_MAPS);

    cvt_bias_kernel<<<8, 256, 0, stream>>>(K1b, V1b, bias, fcnt);
    cvt_hs_kernel<<<16384, 256, 0, stream>>>((const float4*)hs, (ushort4*)Abf);
    cvt_w_kernel<<<dim3(32, 32, 2), 256, 0, stream>>>(K1w, V1w, Btbf);
    gemm_kernel<<<dim3(N_COLS / 128, M_ROWS / 128), 256, 0, stream>>>(
        Abf, Btbf, bias, RH, CV, valid, fcnt, flist);
    refine_kernel<<<NH * GROUPS_PER_HEAD, 64, 0, stream>>>(
        hs, K1w, K1b, RH, fcnt, flist, valid);
    scan_kernel<<<BS * NH, 64, 0, stream>>>(valid, maps);
    gather_kernel<<<BS * SEQ, 256, 0, stream>>>(CV, maps, bw, out);
}

// Round 6
// 411.142 us; speedup vs baseline: 1.4755x; 1.4755x over previous
//
#include <hip/hip_runtime.h>
#include <hip/hip_bf16.h>
#include <cstdint>

// ---------------- problem dims ----------------
#define BS 8
#define SEQ 2048
#define HDIM 1024
#define NH 16
#define HD 64
#define M_ROWS (BS * SEQ)   // 16384
#define N_COLS (2 * HDIM)   // 2048 GEMM cols: 0..1023 = K1 (dots only), 1024..2047 = V1
#define KDIM HDIM           // 1024

#define DELTA 0.025f
#define FLAG_CAP 32768           // flat flagged-task list; expected ~6200 total

// ---------------- workspace layout (bytes) ----------------
#define OFF_A      ((size_t)0)           // bf16 A [M,K]             33,554,432
#define OFF_BT     ((size_t)33554432)    // bf16 Bt [N,K]             4,194,304
#define OFF_FCNT   ((size_t)37748736)    // int
#define OFF_FLIST  ((size_t)37748800)    // int[FLAG_CAP]               131,072
#define OFF_BIAS   ((size_t)38273088)    // f32 [2048]
#define OFF_CV     ((size_t)41943040)    // f32 CV [M,1024] (V1 only) 67,108,864
#define OFF_VALID  ((size_t)109051904)   // u8 [BS][NH][SEQ]             262,144
#define OFF_MAPS   ((size_t)109314048)   // ushort4 [BS][SEQ][NH]      2,097,152
// total ~111.4 MB

typedef __attribute__((ext_vector_type(8))) __bf16 bf16x8;
typedef __attribute__((ext_vector_type(4))) float f32x4;

// float -> bf16 bits, round-to-nearest-even (inputs are finite)
__device__ __forceinline__ unsigned short f2bf(float f) {
    unsigned int x = __builtin_bit_cast(unsigned int, f);
    unsigned int r = x + 0x7fffu + ((x >> 16) & 1u);
    return (unsigned short)(r >> 16);
}

// async 16B global -> LDS (dest = wave-uniform LDS base + lane*16)
__device__ __forceinline__ void g2l16(const void* gp, void* lp) {
    __builtin_amdgcn_global_load_lds(
        (__attribute__((address_space(1))) void*)(void*)gp,
        (__attribute__((address_space(3))) void*)lp, 16, 0, 0);
}

// ---------------- prep kernels ----------------
__global__ __launch_bounds__(256) void cvt_hs_kernel(const float4* __restrict__ in,
                                                     ushort4* __restrict__ outp) {
    int i = blockIdx.x * 256 + threadIdx.x;   // 4,194,304 total
    float4 v = in[i];
    ushort4 o;
    o.x = f2bf(v.x); o.y = f2bf(v.y); o.z = f2bf(v.z); o.w = f2bf(v.w);
    outp[i] = o;
}

// transpose W [K=1024][N=1024] -> Bt[n][k] (bf16)
__global__ __launch_bounds__(256) void cvt_w_kernel(const float* __restrict__ K1w,
                                                    const float* __restrict__ V1w,
                                                    unsigned short* __restrict__ Bt) {
    __shared__ float tile[32][33];
    const float* W = blockIdx.z ? V1w : K1w;
    int tn = blockIdx.x, tk = blockIdx.y;
    int t = threadIdx.x;
    int r = t >> 3;            // 0..31
    int c4 = (t & 7) * 4;      // 0,4,..,28
    const float4 v = *(const float4*)&W[(size_t)(tk * 32 + r) * 1024 + tn * 32 + c4];
    tile[r][c4 + 0] = v.x; tile[r][c4 + 1] = v.y; tile[r][c4 + 2] = v.z; tile[r][c4 + 3] = v.w;
    __syncthreads();
    int n = tn * 32 + r;
    int k = tk * 32 + c4;
    float f0 = tile[c4 + 0][r], f1 = tile[c4 + 1][r], f2 = tile[c4 + 2][r], f3 = tile[c4 + 3][r];
    size_t obase = ((size_t)blockIdx.z * 1024 + n) * 1024 + k;
    ushort4 o; o.x = f2bf(f0); o.y = f2bf(f1); o.z = f2bf(f2); o.w = f2bf(f3);
    *(ushort4*)&Bt[obase] = o;
}

__global__ void cvt_bias_kernel(const float* __restrict__ K1b, const float* __restrict__ V1b,
                                float* __restrict__ bias, int* __restrict__ fcnt) {
    int i = blockIdx.x * 256 + threadIdx.x;   // 2048 total
    bias[i] = (i < 1024) ? K1b[i] : V1b[i - 1024];
    if (i == 0) *fcnt = 0;
}

// ---------------- GEMM + fused dots ----------------
// A [M,K] bf16, Bt [N,K] bf16. 128x128 tile, BK=32, 4 waves 2x2.
// Blocks with n0 <  1024: each wave's 64x64 block == one head's K1 slab ->
//   compute dots = sum_d relu(acc+bias)*RH in-register, write valid + flag list.
//   K-half of C is NEVER stored.
// Blocks with n0 >= 1024: store relu(acc+bias) into CV [M][1024].
__global__ __launch_bounds__(256) void gemm_kernel(const unsigned short* __restrict__ Abf,
                                                   const unsigned short* __restrict__ Btbf,
                                                   const float* __restrict__ bias,
                                                   const float* __restrict__ RH,
                                                   float* __restrict__ CV,
                                                   unsigned char* __restrict__ valid,
                                                   int* __restrict__ fcnt,
                                                   int* __restrict__ flist) {
    constexpr int K = KDIM, BK = 32;
    __shared__ unsigned short As[128 * BK];   // row-major [128][32]
    __shared__ unsigned short Bs[128 * BK];
    const int t = threadIdx.x;
    const int wave = t >> 6, lane = t & 63;
    const int wm = wave >> 1, wn = wave & 1;
    const int l16 = lane & 15, quad = lane >> 4;
    const int m0 = blockIdx.y * 128, n0 = blockIdx.x * 128;

    f32x4 zero4 = {0.f, 0.f, 0.f, 0.f};
    f32x4 acc[4][4];
#pragma unroll
    for (int i = 0; i < 4; i++)
#pragma unroll
        for (int j = 0; j < 4; j++) acc[i][j] = zero4;

    const int srow = t >> 2;          // 0..63
    const int sk = (t & 3) * 8;       // k element offset of this lane's 16B
    const unsigned short* gA = Abf + (size_t)(m0 + srow) * K + sk;
    const unsigned short* gB = Btbf + (size_t)(n0 + srow) * K + sk;
    char* lAs = (char*)As + (size_t)wave * 1024;
    char* lBs = (char*)Bs + (size_t)wave * 1024;

    for (int k0 = 0; k0 < K; k0 += BK) {
        g2l16(gA + k0, lAs);
        g2l16(gA + (size_t)64 * K + k0, lAs + 4096);
        g2l16(gB + k0, lBs);
        g2l16(gB + (size_t)64 * K + k0, lBs + 4096);
        __syncthreads();   // drains global_load_lds (vmcnt) + barrier
        bf16x8 af[4], bfr[4];
#pragma unroll
        for (int mt = 0; mt < 4; mt++)
            af[mt] = *(const bf16x8*)&As[(wm * 64 + mt * 16 + l16) * BK + quad * 8];
#pragma unroll
        for (int nt = 0; nt < 4; nt++)
            bfr[nt] = *(const bf16x8*)&Bs[(wn * 64 + nt * 16 + l16) * BK + quad * 8];
#pragma unroll
        for (int mt = 0; mt < 4; mt++)
#pragma unroll
            for (int nt = 0; nt < 4; nt++)
                acc[mt][nt] = __builtin_amdgcn_mfma_f32_16x16x32_bf16(af[mt], bfr[nt], acc[mt][nt], 0, 0, 0);
        __syncthreads();
    }
    // C/D fragment: row = quad*4 + reg, col = l16 (within each 16x16 tile)
    if (n0 < HDIM) {
        // ---- fused dots: this wave's head ----
        const int n = (n0 >> 6) + wn;
        float rh[4], bv[4];
#pragma unroll
        for (int nt = 0; nt < 4; nt++) {
            int col = n * 64 + nt * 16 + l16;
            rh[nt] = RH[col];
            bv[nt] = bias[col];
        }
#pragma unroll
        for (int mt = 0; mt < 4; mt++) {
#pragma unroll
            for (int r = 0; r < 4; r++) {
                float p = 0.f;
#pragma unroll
                for (int nt = 0; nt < 4; nt++)
                    p += fmaxf(acc[mt][nt][r] + bv[nt], 0.f) * rh[nt];
#pragma unroll
                for (int s = 8; s >= 1; s >>= 1) p += __shfl_xor(p, s, 64);
                if (l16 == 0) {
                    int row = m0 + wm * 64 + mt * 16 + quad * 4 + r;   // b*SEQ + l
                    int b = row >> 11, l = row & (SEQ - 1);
                    valid[((size_t)b * NH + n) * SEQ + l] = (p > 0.5f) ? 1 : 0;
                    if (fabsf(p - 0.5f) < DELTA) {
                        int idx = atomicAdd(fcnt, 1);
                        if (idx < FLAG_CAP) flist[idx] = row * NH + n;
                    }
                }
            }
        }
    } else {
        // ---- V-half: bias + relu, store to CV ----
        const int nv0 = n0 - HDIM;
#pragma unroll
        for (int mt = 0; mt < 4; mt++) {
            int gm = m0 + wm * 64 + mt * 16 + quad * 4;
#pragma unroll
            for (int nt = 0; nt < 4; nt++) {
                int gn = nv0 + wn * 64 + nt * 16 + l16;
                float bvv = bias[HDIM + gn];
#pragma unroll
                for (int r = 0; r < 4; r++)
                    CV[(size_t)(gm + r) * HDIM + gn] = fmaxf(acc[mt][nt][r] + bvv, 0.f);
            }
        }
    }
}

// ---------------- exact fp64 refinement, v6 ----------------
// Flat task list; 4 waves/block, ONE task per wave -> ~6200 active waves
// (~6/SIMD TLP). Lane d owns dim d; weights lane-coalesced (K1w + n*64 + d,
// stride 1024 over k). Latency hiding is INTRA-iteration: each k-group loads
// 32 independent weight dwords + 8 uniform float4 x's (40 VMEM, no deps),
// one waitcnt, then 32 v_fma_f64. R2 evidence shows the compiler batches
// loads within an unrolled body (one exposed latency per group); R4/R5's
// cross-iteration rotation was defeated by the scheduler (VGPR sank to 32).
__global__ __launch_bounds__(256) void refine_kernel(const float* __restrict__ hs,
                                                     const float* __restrict__ K1w,
                                                     const float* __restrict__ K1b,
                                                     const float* __restrict__ RH,
                                                     const int* __restrict__ fcnt,
                                                     const int* __restrict__ flist,
                                                     unsigned char* __restrict__ valid) {
    int cnt = *fcnt;
    if (cnt > FLAG_CAP) cnt = FLAG_CAP;
    const int wave = threadIdx.x >> 6, d = threadIdx.x & 63;
    const int task = blockIdx.x * 4 + wave;
    if (task >= cnt) return;

    const int code = flist[task];
    const int n = code & (NH - 1);
    const int bl = code >> 4;               // b*SEQ + l
    const float* x = hs + (size_t)bl * HDIM;
    const float* wp = K1w + n * 64 + d;     // stride 1024 over k, lane-coalesced

    double acc0 = 0.0, acc1 = 0.0, acc2 = 0.0, acc3 = 0.0;
    for (int k = 0; k < KDIM; k += 32) {
        float w[32];
#pragma unroll
        for (int u = 0; u < 32; u++)
            w[u] = wp[(size_t)(k + u) * 1024];
        float4 xv[8];
#pragma unroll
        for (int u = 0; u < 8; u++)
            xv[u] = *(const float4*)(x + k + u * 4);
#pragma unroll
        for (int u = 0; u < 8; u++) {
            acc0 += (double)xv[u].x * (double)w[u * 4 + 0];
            acc1 += (double)xv[u].y * (double)w[u * 4 + 1];
            acc2 += (double)xv[u].z * (double)w[u * 4 + 2];
            acc3 += (double)xv[u].w * (double)w[u * 4 + 3];
        }
    }
    double k1 = ((acc0 + acc1) + (acc2 + acc3)) + (double)K1b[n * 64 + d];
    if (k1 < 0.0) k1 = 0.0;
    double contrib = k1 * (double)RH[n * 64 + d];
#pragma unroll
    for (int s = 32; s >= 1; s >>= 1) contrib += __shfl_xor(contrib, s, 64);
    if (d == 0) {
        int b = bl >> 11, l = bl & (SEQ - 1);
        valid[((size_t)b * NH + n) * SEQ + l] = (contrib > 0.5) ? 1 : 0;
    }
}

// ---------------- nearest-valid scans ----------------
// one block (64 threads) per (b,n). Lane i owns positions [32i, 32i+32).
__global__ __launch_bounds__(64) void scan_kernel(const unsigned char* __restrict__ valid,
                                                  ushort4* __restrict__ maps) {
    int bn = blockIdx.x;                 // b*NH + n
    int b = bn >> 4, n = bn & (NH - 1);
    int lane = threadIdx.x;
    __shared__ unsigned int summ[64];

    const unsigned char* vp = valid + (size_t)bn * SEQ + lane * 32;
    uint4 c0 = *(const uint4*)vp;
    uint4 c1 = *(const uint4*)(vp + 16);
    unsigned int wds[8] = {c0.x, c0.y, c0.z, c0.w, c1.x, c1.y, c1.z, c1.w};
    unsigned int mask = 0;
#pragma unroll
    for (int i = 0; i < 8; i++) {
#pragma unroll
        for (int j = 0; j < 4; j++)
            mask |= (((wds[i] >> (8 * j)) & 0xffu) ? 1u : 0u) << (i * 4 + j);
    }

    // ---- forward ----
    int cnt = 0, va = 0, vb = 0;
#pragma unroll
    for (int tt = 0; tt < 32; tt++) {
        if (mask & (1u << tt)) { vb = va; va = lane * 32 + tt; cnt++; }
    }
    summ[lane] = (unsigned)((cnt > 2 ? 2 : cnt) | (va << 2) | (vb << 13));
    __syncthreads();
    int a = 0, bb_ = 0;
    for (int tt = 0; tt < lane; tt++) {
        unsigned s = summ[tt];
        int c = s & 3, sva = (s >> 2) & 2047, svb = (s >> 13) & 2047;
        if (c >= 2) { a = sva; bb_ = svb; }
        else if (c == 1) { bb_ = a; a = sva; }
    }
    unsigned int fres[32];
#pragma unroll
    for (int tt = 0; tt < 32; tt++) {
        if (mask & (1u << tt)) { bb_ = a; a = lane * 32 + tt; }
        fres[tt] = (unsigned)a | ((unsigned)bb_ << 16);
    }
    __syncthreads();

    // ---- backward (mirrored values) ----
    unsigned int maskb = mask;
    if (lane == 63) maskb &= ~(1u << 31);   // exclude j = L-1
    cnt = 0; va = 0; vb = 0;
#pragma unroll
    for (int tt = 31; tt >= 0; tt--) {
        if (maskb & (1u << tt)) { vb = va; va = (SEQ - 1) - (lane * 32 + tt); cnt++; }
    }
    summ[lane] = (unsigned)((cnt > 2 ? 2 : cnt) | (va << 2) | (vb << 13));
    __syncthreads();
    int a2 = SEQ - 1, b2 = SEQ - 1;
    for (int tt = 63; tt > lane; tt--) {
        unsigned s = summ[tt];
        int c = s & 3, sva = (s >> 2) & 2047, svb = (s >> 13) & 2047;
        if (c >= 2) { a2 = sva; b2 = svb; }
        else if (c == 1) { b2 = a2; a2 = sva; }
    }
#pragma unroll
    for (int tt = 31; tt >= 0; tt--) {
        int j = lane * 32 + tt;
        if (maskb & (1u << tt)) { b2 = a2; a2 = (SEQ - 1) - j; }
        unsigned f = fres[tt];
        maps[((size_t)b * SEQ + j) * NH + n] =
            make_ushort4((unsigned short)(f & 0xffffu), (unsigned short)(f >> 16),
                         (unsigned short)a2, (unsigned short)b2);
    }
}

// ---------------- gather + weighted sum (CV layout [M][1024]) ----------------
__global__ __launch_bounds__(256) void gather_kernel(const float* __restrict__ CV,
                                                     const ushort4* __restrict__ maps,
                                                     const float* __restrict__ bw,
                                                     float* __restrict__ out) {
    int bl = blockIdx.x;
    int t = threadIdx.x, n = t >> 4, q = t & 15;
    int b = bl >> 11;
    ushort4 m = maps[(size_t)bl * NH + n];
    const float4 w = *(const float4*)&bw[n * 4];
    size_t colbase = (size_t)(n * 64 + q * 4);
    size_t rowb = (size_t)b * SEQ;
    const float4 v0 = *(const float4*)&CV[(rowb + m.x) * HDIM + colbase];
    const float4 v1 = *(const float4*)&CV[(rowb + m.y) * HDIM + colbase];
    const float4 v2 = *(const float4*)&CV[(rowb + m.z) * HDIM + colbase];
    const float4 v3 = *(const float4*)&CV[(rowb + m.w) * HDIM + colbase];
    float4 o;
    o.x = w.x * v0.x + w.y * v1.x + w.z * v2.x + w.w * v3.x;
    o.y = w.x * v0.y + w.y * v1.y + w.z * v2.y + w.w * v3.y;
    o.z = w.x * v0.z + w.y * v1.z + w.z * v2.z + w.w * v3.z;
    o.w = w.x * v0.w + w.y * v1.w + w.z * v2.w + w.w * v3.w;
    *(float4*)&out[(size_t)bl * (NH * HD) + n * 64 + q * 4] = o;
}

// ---------------- launch ----------------
extern "C" void kernel_launch(void* const* d_in, const int* in_sizes, int n_in,
                              void* d_out, int out_size, void* d_ws, size_t ws_size,
                              hipStream_t stream) {
    (void)in_sizes; (void)n_in; (void)out_size; (void)ws_size;
    const float* hs  = (const float*)d_in[0];
    const float* K1w = (const float*)d_in[1];
    const float* K1b = (const float*)d_in[2];
    const float* V1w = (const float*)d_in[3];
    const float* V1b = (const float*)d_in[4];
    const float* bw  = (const float*)d_in[5];
    const float* RH  = (const float*)d_in[6];
    float* out = (float*)d_out;
    char* ws = (char*)d_ws;

    unsigned short* Abf  = (unsigned short*)(ws + OFF_A);
    unsigned short* Btbf = (unsigned short*)(ws + OFF_BT);
    int* fcnt = (int*)(ws + OFF_FCNT);
    int* flist = (int*)(ws + OFF_FLIST);
    float* bias  = (float*)(ws + OFF_BIAS);
    float* CV    = (float*)(ws + OFF_CV);
    unsigned char* valid = (unsigned char*)(ws + OFF_VALID);
    ushort4* maps = (ushort4*)(ws + OFF_MAPS);

    cvt_bias_kernel<<<8, 256, 0, stream>>>(K1b, V1b, bias, fcnt);
    cvt_hs_kernel<<<16384, 256, 0, stream>>>((const float4*)hs, (ushort4*)Abf);
    cvt_w_kernel<<<dim3(32, 32, 2), 256, 0, stream>>>(K1w, V1w, Btbf);
    gemm_kernel<<<dim3(N_COLS / 128, M_ROWS / 128), 256, 0, stream>>>(
        Abf, Btbf, bias, RH, CV, valid, fcnt, flist);
    refine_kernel<<<FLAG_CAP / 4, 256, 0, stream>>>(
        hs, K1w, K1b, RH, fcnt, flist, valid);
    scan_kernel<<<BS * NH, 64, 0, stream>>>(valid, maps);
    gather_kernel<<<BS * SEQ, 256, 0, stream>>>(CV, maps, bw, out);
}

// Round 7
// 375.097 us; speedup vs baseline: 1.6173x; 1.0961x over previous
//
#include <hip/hip_runtime.h>
#include <hip/hip_bf16.h>
#include <cstdint>

// ---------------- problem dims ----------------
#define BS 8
#define SEQ 2048
#define HDIM 1024
#define NH 16
#define HD 64
#define M_ROWS (BS * SEQ)   // 16384
#define N_COLS (2 * HDIM)   // 2048 GEMM cols: 0..1023 = K1 (dots only), 1024..2047 = V1
#define KDIM HDIM           // 1024

#define DELTA 0.025f
#define FLAG_CAP 32768           // flat flagged-task list; expected ~6200 total

// ---------------- workspace layout (bytes) ----------------
#define OFF_A      ((size_t)0)           // bf16 A [M,K]             33,554,432
#define OFF_BT     ((size_t)33554432)    // bf16 Bt [N,K]             4,194,304
#define OFF_FCNT   ((size_t)37748736)    // int
#define OFF_FLIST  ((size_t)37748800)    // int[FLAG_CAP]               131,072
#define OFF_BIAS   ((size_t)37879872)    // f32 [2048]
#define OFF_CVH    ((size_t)41943040)    // bf16 CV [M,1024]          33,554,432
#define OFF_VALID  ((size_t)75497472)    // u8 [BS][NH][SEQ]             262,144
#define OFF_MAPS   ((size_t)75759616)    // ushort4 [BS][SEQ][NH]      2,097,152
// total ~78 MB

typedef __attribute__((ext_vector_type(8))) __bf16 bf16x8;
typedef __attribute__((ext_vector_type(4))) float f32x4;

// float -> bf16 bits, round-to-nearest-even (inputs are finite)
__device__ __forceinline__ unsigned short f2bf(float f) {
    unsigned int x = __builtin_bit_cast(unsigned int, f);
    unsigned int r = x + 0x7fffu + ((x >> 16) & 1u);
    return (unsigned short)(r >> 16);
}
__device__ __forceinline__ float bf2f(unsigned short u) {
    return __builtin_bit_cast(float, (unsigned int)u << 16);
}

// async 16B global -> LDS (dest = wave-uniform LDS base + lane*16)
__device__ __forceinline__ void g2l16(const void* gp, void* lp) {
    __builtin_amdgcn_global_load_lds(
        (__attribute__((address_space(1))) void*)(void*)gp,
        (__attribute__((address_space(3))) void*)lp, 16, 0, 0);
}

// ---------------- fused prep: hs->bf16 | W transpose->bf16 | bias+fcnt ----------------
__global__ __launch_bounds__(256) void prep_kernel(const float4* __restrict__ hs4,
                                                   ushort4* __restrict__ Abf4,
                                                   const float* __restrict__ K1w,
                                                   const float* __restrict__ V1w,
                                                   unsigned short* __restrict__ Bt,
                                                   const float* __restrict__ K1b,
                                                   const float* __restrict__ V1b,
                                                   float* __restrict__ bias,
                                                   int* __restrict__ fcnt) {
    __shared__ float tile[32][33];
    const int blk = blockIdx.x;
    const int t = threadIdx.x;
    if (blk < 16384) {
        int i = blk * 256 + t;            // 4,194,304 float4s
        float4 v = hs4[i];
        ushort4 o;
        o.x = f2bf(v.x); o.y = f2bf(v.y); o.z = f2bf(v.z); o.w = f2bf(v.w);
        Abf4[i] = o;
    } else if (blk < 18432) {
        int lb = blk - 16384;             // 0..2047 = tn + 32*tk + 1024*z
        int z = lb >> 10;
        int tk = (lb >> 5) & 31;
        int tn = lb & 31;
        const float* W = z ? V1w : K1w;
        int r = t >> 3;                   // 0..31
        int c4 = (t & 7) * 4;             // 0,4,..,28
        const float4 v = *(const float4*)&W[(size_t)(tk * 32 + r) * 1024 + tn * 32 + c4];
        tile[r][c4 + 0] = v.x; tile[r][c4 + 1] = v.y;
        tile[r][c4 + 2] = v.z; tile[r][c4 + 3] = v.w;
        __syncthreads();
        int n = tn * 32 + r;
        int k = tk * 32 + c4;
        ushort4 o;
        o.x = f2bf(tile[c4 + 0][r]); o.y = f2bf(tile[c4 + 1][r]);
        o.z = f2bf(tile[c4 + 2][r]); o.w = f2bf(tile[c4 + 3][r]);
        *(ushort4*)&Bt[((size_t)z * 1024 + n) * 1024 + k] = o;
    } else {
        int i = (blk - 18432) * 256 + t;  // 0..2047
        bias[i] = (i < 1024) ? K1b[i] : V1b[i - 1024];
        if (i == 0) *fcnt = 0;
    }
}

// ---------------- GEMM + fused dots ----------------
// A [M,K] bf16, Bt [N,K] bf16. 128x128 tile, BK=64, 4 waves 2x2, 16 K-iters.
// LDS rows are 128 B; to avoid 16-way bank conflicts under global_load_lds's
// lane-ordered dest, the SOURCE k-group is XOR-swizzled: physical 16B-group
// g for row r holds logical group g^(r&7). Fragment reads apply the same XOR
// -> 16 lanes span 8 bank-groups (2-way, free). Permutation stays within each
// row's 128 B so global coalescing is unchanged.
// n0 <  1024: fused dots epilogue (valid + flag list), K-half never stored.
// n0 >= 1024: relu(acc+bias) -> CVh (bf16) [M][1024].
__global__ __launch_bounds__(256) void gemm_kernel(const unsigned short* __restrict__ Abf,
                                                   const unsigned short* __restrict__ Btbf,
                                                   const float* __restrict__ bias,
                                                   const float* __restrict__ RH,
                                                   unsigned short* __restrict__ CVh,
                                                   unsigned char* __restrict__ valid,
                                                   int* __restrict__ fcnt,
                                                   int* __restrict__ flist) {
    constexpr int K = KDIM, BK = 64;
    __shared__ unsigned short As[128 * BK];   // [row][64] with XOR-swizzled groups
    __shared__ unsigned short Bs[128 * BK];
    const int t = threadIdx.x;
    const int wave = t >> 6, lane = t & 63;
    const int wm = wave >> 1, wn = wave & 1;
    const int l16 = lane & 15, quad = lane >> 4;
    const int sw = l16 & 7;                  // read-side XOR key (r&7 == l16&7)
    const int m0 = blockIdx.y * 128, n0 = blockIdx.x * 128;

    f32x4 zero4 = {0.f, 0.f, 0.f, 0.f};
    f32x4 acc[4][4];
#pragma unroll
    for (int i = 0; i < 4; i++)
#pragma unroll
        for (int j = 0; j < 4; j++) acc[i][j] = zero4;

    // staging roles: rr = row 0..31 (per issue), g = 16B-group 0..7
    const int rr = t >> 3;
    const int gsw = (t ^ (t >> 3)) & 7;      // g ^ (row&7); row&7 invariant across issues
    const unsigned short* gA = Abf + (size_t)(m0 + rr) * K + gsw * 8;
    const unsigned short* gB = Btbf + (size_t)(n0 + rr) * K + gsw * 8;
    char* lAs = (char*)As + (size_t)wave * 1024;
    char* lBs = (char*)Bs + (size_t)wave * 1024;

    for (int k0 = 0; k0 < K; k0 += BK) {
#pragma unroll
        for (int i = 0; i < 4; i++)
            g2l16(gA + (size_t)i * 32 * K + k0, lAs + i * 4096);
#pragma unroll
        for (int i = 0; i < 4; i++)
            g2l16(gB + (size_t)i * 32 * K + k0, lBs + i * 4096);
        __syncthreads();   // drains global_load_lds (vmcnt) + barrier
#pragma unroll
        for (int h = 0; h < 2; h++) {
            bf16x8 af[4], bfr[4];
            const int hq = h * 4 + quad;
#pragma unroll
            for (int mt = 0; mt < 4; mt++)
                af[mt] = *(const bf16x8*)&As[(wm * 64 + mt * 16 + l16) * BK + (hq ^ sw) * 8];
#pragma unroll
            for (int nt = 0; nt < 4; nt++)
                bfr[nt] = *(const bf16x8*)&Bs[(wn * 64 + nt * 16 + l16) * BK + (hq ^ sw) * 8];
#pragma unroll
            for (int mt = 0; mt < 4; mt++)
#pragma unroll
                for (int nt = 0; nt < 4; nt++)
                    acc[mt][nt] = __builtin_amdgcn_mfma_f32_16x16x32_bf16(af[mt], bfr[nt], acc[mt][nt], 0, 0, 0);
        }
        __syncthreads();
    }
    // C/D fragment: row = quad*4 + reg, col = l16 (within each 16x16 tile)
    if (n0 < HDIM) {
        // ---- fused dots: this wave's head ----
        const int n = (n0 >> 6) + wn;
        float rh[4], bv[4];
#pragma unroll
        for (int nt = 0; nt < 4; nt++) {
            int col = n * 64 + nt * 16 + l16;
            rh[nt] = RH[col];
            bv[nt] = bias[col];
        }
#pragma unroll
        for (int mt = 0; mt < 4; mt++) {
#pragma unroll
            for (int r = 0; r < 4; r++) {
                float p = 0.f;
#pragma unroll
                for (int nt = 0; nt < 4; nt++)
                    p += fmaxf(acc[mt][nt][r] + bv[nt], 0.f) * rh[nt];
#pragma unroll
                for (int s = 8; s >= 1; s >>= 1) p += __shfl_xor(p, s, 64);
                if (l16 == 0) {
                    int row = m0 + wm * 64 + mt * 16 + quad * 4 + r;   // b*SEQ + l
                    int b = row >> 11, l = row & (SEQ - 1);
                    valid[((size_t)b * NH + n) * SEQ + l] = (p > 0.5f) ? 1 : 0;
                    if (fabsf(p - 0.5f) < DELTA) {
                        int idx = atomicAdd(fcnt, 1);
                        if (idx < FLAG_CAP) flist[idx] = row * NH + n;
                    }
                }
            }
        }
    } else {
        // ---- V-half: bias + relu, store bf16 to CVh ----
        const int nv0 = n0 - HDIM;
#pragma unroll
        for (int mt = 0; mt < 4; mt++) {
            int gm = m0 + wm * 64 + mt * 16 + quad * 4;
#pragma unroll
            for (int nt = 0; nt < 4; nt++) {
                int gn = nv0 + wn * 64 + nt * 16 + l16;
                float bvv = bias[HDIM + gn];
#pragma unroll
                for (int r = 0; r < 4; r++)
                    CVh[(size_t)(gm + r) * HDIM + gn] = f2bf(fmaxf(acc[mt][nt][r] + bvv, 0.f));
            }
        }
    }
}

// ---------------- exact fp64 refinement (R6 structure — works) ----------------
// Flat task list; 4 waves/block, ONE task per wave. Intra-iteration latency
// hiding: 32 independent weight dwords + 8 uniform float4 x's per k-group,
// one waitcnt, then 32 v_fma_f64.
__global__ __launch_bounds__(256) void refine_kernel(const float* __restrict__ hs,
                                                     const float* __restrict__ K1w,
                                                     const float* __restrict__ K1b,
                                                     const float* __restrict__ RH,
                                                     const int* __restrict__ fcnt,
                                                     const int* __restrict__ flist,
                                                     unsigned char* __restrict__ valid) {
    int cnt = *fcnt;
    if (cnt > FLAG_CAP) cnt = FLAG_CAP;
    const int wave = threadIdx.x >> 6, d = threadIdx.x & 63;
    const int task = blockIdx.x * 4 + wave;
    if (task >= cnt) return;

    const int code = flist[task];
    const int n = code & (NH - 1);
    const int bl = code >> 4;               // b*SEQ + l
    const float* x = hs + (size_t)bl * HDIM;
    const float* wp = K1w + n * 64 + d;     // stride 1024 over k, lane-coalesced

    double acc0 = 0.0, acc1 = 0.0, acc2 = 0.0, acc3 = 0.0;
    for (int k = 0; k < KDIM; k += 32) {
        float w[32];
#pragma unroll
        for (int u = 0; u < 32; u++)
            w[u] = wp[(size_t)(k + u) * 1024];
        float4 xv[8];
#pragma unroll
        for (int u = 0; u < 8; u++)
            xv[u] = *(const float4*)(x + k + u * 4);
#pragma unroll
        for (int u = 0; u < 8; u++) {
            acc0 += (double)xv[u].x * (double)w[u * 4 + 0];
            acc1 += (double)xv[u].y * (double)w[u * 4 + 1];
            acc2 += (double)xv[u].z * (double)w[u * 4 + 2];
            acc3 += (double)xv[u].w * (double)w[u * 4 + 3];
        }
    }
    double k1 = ((acc0 + acc1) + (acc2 + acc3)) + (double)K1b[n * 64 + d];
    if (k1 < 0.0) k1 = 0.0;
    double contrib = k1 * (double)RH[n * 64 + d];
#pragma unroll
    for (int s = 32; s >= 1; s >>= 1) contrib += __shfl_xor(contrib, s, 64);
    if (d == 0) {
        int b = bl >> 11, l = bl & (SEQ - 1);
        valid[((size_t)b * NH + n) * SEQ + l] = (contrib > 0.5) ? 1 : 0;
    }
}

// ---------------- nearest-valid scans ----------------
// one block (64 threads) per (b,n). Lane i owns positions [32i, 32i+32).
__global__ __launch_bounds__(64) void scan_kernel(const unsigned char* __restrict__ valid,
                                                  ushort4* __restrict__ maps) {
    int bn = blockIdx.x;                 // b*NH + n
    int b = bn >> 4, n = bn & (NH - 1);
    int lane = threadIdx.x;
    __shared__ unsigned int summ[64];

    const unsigned char* vp = valid + (size_t)bn * SEQ + lane * 32;
    uint4 c0 = *(const uint4*)vp;
    uint4 c1 = *(const uint4*)(vp + 16);
    unsigned int wds[8] = {c0.x, c0.y, c0.z, c0.w, c1.x, c1.y, c1.z, c1.w};
    unsigned int mask = 0;
#pragma unroll
    for (int i = 0; i < 8; i++) {
#pragma unroll
        for (int j = 0; j < 4; j++)
            mask |= (((wds[i] >> (8 * j)) & 0xffu) ? 1u : 0u) << (i * 4 + j);
    }

    // ---- forward ----
    int cnt = 0, va = 0, vb = 0;
#pragma unroll
    for (int tt = 0; tt < 32; tt++) {
        if (mask & (1u << tt)) { vb = va; va = lane * 32 + tt; cnt++; }
    }
    summ[lane] = (unsigned)((cnt > 2 ? 2 : cnt) | (va << 2) | (vb << 13));
    __syncthreads();
    int a = 0, bb_ = 0;
    for (int tt = 0; tt < lane; tt++) {
        unsigned s = summ[tt];
        int c = s & 3, sva = (s >> 2) & 2047, svb = (s >> 13) & 2047;
        if (c >= 2) { a = sva; bb_ = svb; }
        else if (c == 1) { bb_ = a; a = sva; }
    }
    unsigned int fres[32];
#pragma unroll
    for (int tt = 0; tt < 32; tt++) {
        if (mask & (1u << tt)) { bb_ = a; a = lane * 32 + tt; }
        fres[tt] = (unsigned)a | ((unsigned)bb_ << 16);
    }
    __syncthreads();

    // ---- backward (mirrored values) ----
    unsigned int maskb = mask;
    if (lane == 63) maskb &= ~(1u << 31);   // exclude j = L-1
    cnt = 0; va = 0; vb = 0;
#pragma unroll
    for (int tt = 31; tt >= 0; tt--) {
        if (maskb & (1u << tt)) { vb = va; va = (SEQ - 1) - (lane * 32 + tt); cnt++; }
    }
    summ[lane] = (unsigned)((cnt > 2 ? 2 : cnt) | (va << 2) | (vb << 13));
    __syncthreads();
    int a2 = SEQ - 1, b2 = SEQ - 1;
    for (int tt = 63; tt > lane; tt--) {
        unsigned s = summ[tt];
        int c = s & 3, sva = (s >> 2) & 2047, svb = (s >> 13) & 2047;
        if (c >= 2) { a2 = sva; b2 = svb; }
        else if (c == 1) { b2 = a2; a2 = sva; }
    }
#pragma unroll
    for (int tt = 31; tt >= 0; tt--) {
        int j = lane * 32 + tt;
        if (maskb & (1u << tt)) { b2 = a2; a2 = (SEQ - 1) - j; }
        unsigned f = fres[tt];
        maps[((size_t)b * SEQ + j) * NH + n] =
            make_ushort4((unsigned short)(f & 0xffffu), (unsigned short)(f >> 16),
                         (unsigned short)a2, (unsigned short)b2);
    }
}

// ---------------- gather + weighted sum (CVh bf16 [M][1024]) ----------------
__global__ __launch_bounds__(256) void gather_kernel(const unsigned short* __restrict__ CVh,
                                                     const ushort4* __restrict__ maps,
                                                     const float* __restrict__ bw,
                                                     float* __restrict__ out) {
    int bl = blockIdx.x;
    int t = threadIdx.x, n = t >> 4, q = t & 15;
    int b = bl >> 11;
    ushort4 m = maps[(size_t)bl * NH + n];
    const float4 w = *(const float4*)&bw[n * 4];
    size_t colbase = (size_t)(n * 64 + q * 4);
    size_t rowb = (size_t)b * SEQ;
    const ushort4 u0 = *(const ushort4*)&CVh[(rowb + m.x) * HDIM + colbase];
    const ushort4 u1 = *(const ushort4*)&CVh[(rowb + m.y) * HDIM + colbase];
    const ushort4 u2 = *(const ushort4*)&CVh[(rowb + m.z) * HDIM + colbase];
    const ushort4 u3 = *(const ushort4*)&CVh[(rowb + m.w) * HDIM + colbase];
    float4 o;
    o.x = w.x * bf2f(u0.x) + w.y * bf2f(u1.x) + w.z * bf2f(u2.x) + w.w * bf2f(u3.x);
    o.y = w.x * bf2f(u0.y) + w.y * bf2f(u1.y) + w.z * bf2f(u2.y) + w.w * bf2f(u3.y);
    o.z = w.x * bf2f(u0.z) + w.y * bf2f(u1.z) + w.z * bf2f(u2.z) + w.w * bf2f(u3.z);
    o.w = w.x * bf2f(u0.w) + w.y * bf2f(u1.w) + w.z * bf2f(u2.w) + w.w * bf2f(u3.w);
    *(float4*)&out[(size_t)bl * (NH * HD) + n * 64 + q * 4] = o;
}

// ---------------- launch ----------------
extern "C" void kernel_launch(void* const* d_in, const int* in_sizes, int n_in,
                              void* d_out, int out_size, void* d_ws, size_t ws_size,
                              hipStream_t stream) {
    (void)in_sizes; (void)n_in; (void)out_size; (void)ws_size;
    const float* hs  = (const float*)d_in[0];
    const float* K1w = (const float*)d_in[1];
    const float* K1b = (const float*)d_in[2];
    const float* V1w = (const float*)d_in[3];
    const float* V1b = (const float*)d_in[4];
    const float* bw  = (const float*)d_in[5];
    const float* RH  = (const float*)d_in[6];
    float* out = (float*)d_out;
    char* ws = (char*)d_ws;

    unsigned short* Abf  = (unsigned short*)(ws + OFF_A);
    unsigned short* Btbf = (unsigned short*)(ws + OFF_BT);
    int* fcnt = (int*)(ws + OFF_FCNT);
    int* flist = (int*)(ws + OFF_FLIST);
    float* bias  = (float*)(ws + OFF_BIAS);
    unsigned short* CVh = (unsigned short*)(ws + OFF_CVH);
    unsigned char* valid = (unsigned char*)(ws + OFF_VALID);
    ushort4* maps = (ushort4*)(ws + OFF_MAPS);

    prep_kernel<<<18440, 256, 0, stream>>>((const float4*)hs, (ushort4*)Abf,
                                           K1w, V1w, Btbf, K1b, V1b, bias, fcnt);
    gemm_kernel<<<dim3(N_COLS / 128, M_ROWS / 128), 256, 0, stream>>>(
        Abf, Btbf, bias, RH, CVh, valid, fcnt, flist);
    refine_kernel<<<FLAG_CAP / 4, 256, 0, stream>>>(
        hs, K1w, K1b, RH, fcnt, flist, valid);
    scan_kernel<<<BS * NH, 64, 0, stream>>>(valid, maps);
    gather_kernel<<<BS * SEQ, 256, 0, stream>>>(CVh, maps, bw, out);
}